// Round 1
// baseline (87.211 us; speedup 1.0000x reference)
//
#include <hip/hip_runtime.h>

// out[b,s,e] = W_e[e, tokens[b,s]] + W_p[s,e]
// tokens: (2,2048) int32 ; W_e: (1024,32000) f32 ; W_p: (2048,1024) f32
// out: (2,2048,1024) f32

#define VOCAB 32000
#define EDIM  1024
#define SLEN  2048

__global__ __launch_bounds__(256) void embed_gather_kernel(
    const int*   __restrict__ tokens,
    const float* __restrict__ W_e,
    const float* __restrict__ W_p,
    float*       __restrict__ out)
{
    const int bs = blockIdx.x;          // 0 .. B*S-1  (4096)
    const int s  = bs & (SLEN - 1);
    const int tok = tokens[bs];         // wave-uniform -> scalar broadcast
    const int e0 = threadIdx.x * 4;     // 256 threads * 4 = 1024 = EDIM

    const float4 wp = *reinterpret_cast<const float4*>(&W_p[s * EDIM + e0]);

    // 4 independent scattered gathers (stride V between rows of W_e)
    const float g0 = W_e[(size_t)(e0 + 0) * VOCAB + tok];
    const float g1 = W_e[(size_t)(e0 + 1) * VOCAB + tok];
    const float g2 = W_e[(size_t)(e0 + 2) * VOCAB + tok];
    const float g3 = W_e[(size_t)(e0 + 3) * VOCAB + tok];

    float4 r;
    r.x = g0 + wp.x;
    r.y = g1 + wp.y;
    r.z = g2 + wp.z;
    r.w = g3 + wp.w;

    *reinterpret_cast<float4*>(&out[(size_t)bs * EDIM + e0]) = r;
}

extern "C" void kernel_launch(void* const* d_in, const int* in_sizes, int n_in,
                              void* d_out, int out_size, void* d_ws, size_t ws_size,
                              hipStream_t stream) {
    const int*   tokens = (const int*)d_in[0];
    const float* W_e    = (const float*)d_in[1];
    const float* W_p    = (const float*)d_in[2];
    float*       out    = (float*)d_out;

    const int n_bs = out_size / EDIM;   // B*S = 4096
    embed_gather_kernel<<<n_bs, 256, 0, stream>>>(tokens, W_e, W_p, out);
}

// Round 2
// 43.801 us; speedup vs baseline: 1.9910x; 1.9910x over previous
//
#include <hip/hip_runtime.h>

// out[b,s,e] = W_e[e, tokens[b,s]] + W_p[s,e]
// tokens: (2,2048) int32 ; W_e: (1024,32000) f32 ; W_p: (2048,1024) f32
// out: (2,2048,1024) f32
//
// Strategy: invert the gather. Stream W_e exactly once (coalesced tiles into
// LDS), scatter columns to the token positions that need them. Converts
// 268 MB of random 64B-granule traffic into 131 MB of streaming traffic.

#define VOCAB 32000
#define EDIM  1024
#define SLEN  2048
#define NBS   4096            // B*S
#define VC    128             // vocab chunk width
#define NV    (VOCAB / VC)    // 250
#define EC    64              // e chunk height
#define NE    (EDIM / EC)     // 16
#define MAXN  512             // capacity per vocab chunk (mean occupancy ~16.4)

// ---------- phase 0: zero bucket counters ----------
__global__ void zero_counts_kernel(int* __restrict__ counts) {
    const int i = blockIdx.x * blockDim.x + threadIdx.x;
    if (i < NV) counts[i] = 0;
}

// ---------- phase 1: bucket token occurrences by vocab chunk ----------
__global__ void bucket_tokens_kernel(const int* __restrict__ tokens,
                                     int* __restrict__ counts,  // [NV]
                                     int* __restrict__ lists)   // [NV][MAXN]
{
    const int bs = blockIdx.x * blockDim.x + threadIdx.x;
    if (bs >= NBS) return;
    const int tok  = tokens[bs];
    const int cv   = tok >> 7;          // tok / VC
    const int col  = tok & (VC - 1);
    const int slot = atomicAdd(&counts[cv], 1);
    if (slot < MAXN)
        lists[cv * MAXN + slot] = bs | (col << 12);   // bs<4096 fits 12 bits
}

// ---------- phase 2: stream W_e tiles, scatter to outputs ----------
__global__ __launch_bounds__(256) void scatter_embed_kernel(
    const float* __restrict__ W_e,
    const float* __restrict__ W_p,
    const int*   __restrict__ counts,
    const int*   __restrict__ lists,
    float*       __restrict__ out)
{
    __shared__ float tile[EC][VC + 1];   // stride 129 floats -> conflict-free column reads
    const int cv = blockIdx.x;           // vocab chunk
    const int ce = blockIdx.y;           // e chunk
    const int e0 = ce * EC;
    const int v0 = cv * VC;
    const int t  = threadIdx.x;

    // Load 64x128 f32 tile, coalesced: 32 lanes x float4 cover one row (512 B).
    {
        const int lane = t & 31;
        const int r0   = t >> 5;         // 0..7
        #pragma unroll
        for (int rr = 0; rr < EC / 8; ++rr) {
            const int row = rr * 8 + r0;
            const float4 v = *reinterpret_cast<const float4*>(
                &W_e[(size_t)(e0 + row) * VOCAB + v0 + lane * 4]);
            tile[row][lane * 4 + 0] = v.x;
            tile[row][lane * 4 + 1] = v.y;
            tile[row][lane * 4 + 2] = v.z;
            tile[row][lane * 4 + 3] = v.w;
        }
    }
    __syncthreads();

    int nt = counts[cv];
    if (nt > MAXN) nt = MAXN;            // unreachable for this data; safety clamp
    const int sub = t >> 6;              // wave id 0..3: one token per wave
    const int r   = t & 63;              // e-offset within chunk
    for (int i = sub; i < nt; i += 4) {
        const int entry = lists[cv * MAXN + i];
        const int bs    = entry & 0xFFF;
        const int col   = entry >> 12;
        const int s     = bs & (SLEN - 1);
        // LDS column read: addr = r*129 + col -> bank (r+col)%32, conflict-free
        const float v = tile[r][col] + W_p[(size_t)s * EDIM + e0 + r];
        out[(size_t)bs * EDIM + e0 + r] = v;   // 64 consecutive floats, coalesced
    }
}

// ---------- fallback (ws too small): direct gather, round-1 kernel ----------
__global__ __launch_bounds__(256) void embed_gather_kernel(
    const int*   __restrict__ tokens,
    const float* __restrict__ W_e,
    const float* __restrict__ W_p,
    float*       __restrict__ out)
{
    const int bs  = blockIdx.x;
    const int s   = bs & (SLEN - 1);
    const int tok = tokens[bs];
    const int e0  = threadIdx.x * 4;
    const float4 wp = *reinterpret_cast<const float4*>(&W_p[s * EDIM + e0]);
    const float g0 = W_e[(size_t)(e0 + 0) * VOCAB + tok];
    const float g1 = W_e[(size_t)(e0 + 1) * VOCAB + tok];
    const float g2 = W_e[(size_t)(e0 + 2) * VOCAB + tok];
    const float g3 = W_e[(size_t)(e0 + 3) * VOCAB + tok];
    float4 r; r.x = g0 + wp.x; r.y = g1 + wp.y; r.z = g2 + wp.z; r.w = g3 + wp.w;
    *reinterpret_cast<float4*>(&out[(size_t)bs * EDIM + e0]) = r;
}

extern "C" void kernel_launch(void* const* d_in, const int* in_sizes, int n_in,
                              void* d_out, int out_size, void* d_ws, size_t ws_size,
                              hipStream_t stream) {
    const int*   tokens = (const int*)d_in[0];
    const float* W_e    = (const float*)d_in[1];
    const float* W_p    = (const float*)d_in[2];
    float*       out    = (float*)d_out;

    const size_t counts_bytes = (size_t)NV * sizeof(int);
    const size_t lists_bytes  = (size_t)NV * MAXN * sizeof(int);
    const size_t need = counts_bytes + lists_bytes;

    if (ws_size < need) {
        // workspace too small: fall back to direct gather
        embed_gather_kernel<<<NBS, 256, 0, stream>>>(tokens, W_e, W_p, out);
        return;
    }

    int* counts = (int*)d_ws;
    int* lists  = (int*)((char*)d_ws + counts_bytes);

    zero_counts_kernel<<<1, 256, 0, stream>>>(counts);
    bucket_tokens_kernel<<<NBS / 256, 256, 0, stream>>>(tokens, counts, lists);

    dim3 grid(NV, NE);
    scatter_embed_kernel<<<grid, 256, 0, stream>>>(W_e, W_p, counts, lists, out);
}